// Round 1
// 558.684 us; speedup vs baseline: 1.0232x; 1.0232x over previous
//
#include <hip/hip_runtime.h>
#include <math.h>

// EMRouting: B=8,H=12,W=12,K=3,CIN=16,COUT=32,P=16 -> 1152 positions x 144 votes
#define NPOS 1152
#define NN   144
#define COUT 32
#define PP   16
#define EPSF 1e-7f
#define LOG2PI 1.8378770664093453f

#define MU_OFF   0
#define A_OFF    589824            // 1152*32*16
#define SIG_OFF  626688            // + 1152*32

// DPP helper: butterfly partner move on the VALU pipe (no LDS traffic).
template<int CTRL>
__device__ __forceinline__ float dppf(float x) {
    return __int_as_float(__builtin_amdgcn_update_dpp(
        0, __float_as_int(x), CTRL, 0xf, 0xf, true));
}

// Reduce over the 32-lane half-wave. Steps 1,2 via quad_perm; 4,8 via
// row_half_mirror/row_mirror (involutions pairing sibling groups — valid
// butterfly merges); final 16-cross via one ds_swizzle shuffle.
__device__ __forceinline__ float redmax32(float m) {
    m = fmaxf(m, dppf<0xB1>(m));      // quad_perm [1,0,3,2]
    m = fmaxf(m, dppf<0x4E>(m));      // quad_perm [2,3,0,1]
    m = fmaxf(m, dppf<0x141>(m));     // row_half_mirror
    m = fmaxf(m, dppf<0x140>(m));     // row_mirror
    m = fmaxf(m, __shfl_xor(m, 16, 64));
    return m;
}
__device__ __forceinline__ float redsum32(float s) {
    s += dppf<0xB1>(s);
    s += dppf<0x4E>(s);
    s += dppf<0x141>(s);
    s += dppf<0x140>(s);
    s += __shfl_xor(s, 16, 64);
    return s;
}

// Block = 256 threads = 4 waves. cout = tid&31, n-slot = tid>>5 (8 slots,
// n = slot + 8*j, j=0..17). One barrier per EM iteration: partials ->
// red[it&1] (double-buffered), then ALL threads redundantly finalize their
// own cout lane fully in registers (mu/wp/cl never leave the lane).
__global__ void __launch_bounds__(256, 4)
em_routing_kernel(const float* __restrict__ V,
                  const float* __restrict__ a,
                  const float* __restrict__ Bu,
                  const float* __restrict__ Ba,
                  const float* __restrict__ Rin,
                  float* __restrict__ out)
{
    const int pos  = blockIdx.x;
    const int tid  = threadIdx.x;
    const int c    = tid & 31;   // cout lane
    const int slot = tid >> 5;   // 0..7
    const int wave = tid >> 6;   // 0..3

    const float* Vp = V + (size_t)pos * (NN * COUT * PP);
    const float* Rp = Rin + (size_t)pos * (NN * COUT);

    __shared__ float a_s[NN];
    // [buf][wave][c][ S1[0..15] | S2[16..31] | S0[32] ], stride 36 floats:
    // float4-aligned, 4-way bank aliasing on b128 (acceptable per m136).
    __shared__ __align__(16) float red[2][4][32][36];

    for (int i = tid; i < NN; i += 256) a_s[i] = a[pos * NN + i];
    __syncthreads();

    const float Bu_c = Bu[c];
    const float Ba_c = Ba[c];

    float A_r[PP];    // 1/(2*sigma^2+EPS)
    float B2_r[PP];   // 2*A*mu
    float cl2 = 0.f;  // log(a_out)+log_p1 - sum_p A*mu^2
    float mu[PP], sg[PP];
    float ao = 0.f;

    #pragma unroll
    for (int it = 0; it < 3; ++it) {
        const float lam = 0.01f * (1.f - ((it == 0) ? 0.95f
                                         : (it == 1) ? 0.95f * 0.95f
                                                     : 0.95f * 0.95f * 0.95f));

        float S0 = 0.f, S1[PP], S2[PP];
        #pragma unroll
        for (int p = 0; p < PP; ++p) { S1[p] = 0.f; S2[p] = 0.f; }

        const float4* vq = (const float4*)(Vp + (size_t)slot * (COUT * PP) + c * PP);
        const float*  rq = Rp + slot * COUT + c;

        // depth-1 software pipeline: vote j+1's 64 B are in flight under
        // vote j's softmax/accumulate chain.
        float4 n0 = vq[0], n1 = vq[1], n2 = vq[2], n3 = vq[3];
        float  rv = (it == 0) ? *rq : 0.f;

        #pragma unroll 1
        for (int j = 0; j < 18; ++j) {
            const float4 q0 = n0, q1 = n1, q2 = n2, q3 = n3;
            const float  rc = rv;
            if (j < 17) {
                vq += 1024;                     // 8 votes * 512 floats / 4
                n0 = vq[0]; n1 = vq[1]; n2 = vq[2]; n3 = vq[3];
                if (it == 0) { rq += 256; rv = *rq; }
            }
            const float av = a_s[slot + (j << 3)];

            const float v[PP] = {q0.x,q0.y,q0.z,q0.w, q1.x,q1.y,q1.z,q1.w,
                                 q2.x,q2.y,q2.z,q2.w, q3.x,q3.y,q3.z,q3.w};
            float Rw;
            if (it == 0) {
                Rw = rc * av;                   // initial R from input
            } else {
                // logit = cl - sum_p wp*(v-mu)^2 = cl2 + sum_p (B2 - A*v)*v
                float logit = cl2;
                #pragma unroll
                for (int p = 0; p < PP; ++p) {
                    const float t = fmaf(-A_r[p], v[p], B2_r[p]);
                    logit = fmaf(t, v[p], logit);
                }
                const float m = redmax32(logit);
                const float e = __expf(logit - m);
                const float s = redsum32(e);
                Rw = __fdividef(e, s) * av;
            }
            // M-step accumulation
            S0 += Rw;
            #pragma unroll
            for (int p = 0; p < PP; ++p) {
                const float t = Rw * v[p];
                S1[p] += t;
                S2[p] = fmaf(t, v[p], S2[p]);
            }
        }

        // fold the two n-subsets within the wave
        S0 += __shfl_xor(S0, 32, 64);
        #pragma unroll
        for (int p = 0; p < PP; ++p) {
            S1[p] += __shfl_xor(S1[p], 32, 64);
            S2[p] += __shfl_xor(S2[p], 32, 64);
        }

        float* rb = &red[it & 1][wave][c][0];
        if ((tid & 32) == 0) {
            #pragma unroll
            for (int q = 0; q < 4; ++q)
                ((float4*)rb)[q] = make_float4(S1[4*q], S1[4*q+1], S1[4*q+2], S1[4*q+3]);
            rb[32] = S0;
        } else {
            #pragma unroll
            for (int q = 0; q < 4; ++q)
                ((float4*)rb)[4 + q] = make_float4(S2[4*q], S2[4*q+1], S2[4*q+2], S2[4*q+3]);
        }
        __syncthreads();   // the ONLY barrier in the iteration

        // Finalize: every thread redundantly computes its own c. All 256
        // lanes busy (16 parallel logf chains instead of a 32-thread island).
        float s1[PP], s2[PP], d0 = 0.f;
        #pragma unroll
        for (int p = 0; p < PP; ++p) { s1[p] = 0.f; s2[p] = 0.f; }
        #pragma unroll
        for (int w = 0; w < 4; ++w) {
            const float* rr = &red[it & 1][w][c][0];
            #pragma unroll
            for (int q = 0; q < 4; ++q) {
                const float4 x = ((const float4*)rr)[q];
                s1[4*q] += x.x; s1[4*q+1] += x.y; s1[4*q+2] += x.z; s1[4*q+3] += x.w;
            }
            #pragma unroll
            for (int q = 0; q < 4; ++q) {
                const float4 x = ((const float4*)rr)[4 + q];
                s2[4*q] += x.x; s2[4*q+1] += x.y; s2[4*q+2] += x.z; s2[4*q+3] += x.w;
            }
            d0 += rr[32];
        }

        const float inv = __fdividef(1.f, d0 + EPSF);
        float sumlog = 0.f;
        #pragma unroll
        for (int p = 0; p < PP; ++p) {
            const float m_ = s1[p] * inv;
            float g = (s2[p] - 2.f * m_ * s1[p] + m_ * m_ * d0) * inv;
            g = fmaxf(g, 1e-30f);               // guard cancellation -> log NaN
            mu[p] = m_;
            sg[p] = g;
            sumlog += __logf(g);
        }
        // sum_p cost_h = d0*(P*Beta_u + 0.5*sumlog); x = Lam*(Beta_a - that)
        const float xs  = lam * (Ba_c - d0 * (16.f * Bu_c + 0.5f * sumlog));
        const float nn2 = redsum32(xs * xs);    // l2 over cout, wave-parallel
        const float y   = xs / fmaxf(sqrtf(nn2), 1e-12f);
        ao = 1.f / (1.f + __expf(-y));
        // log_p1 = -0.5*(P*log(2pi) + sumlog) + EPS
        const float cl = __logf(ao) - 0.5f * (16.f * LOG2PI + sumlog) + EPSF;

        // E-step registers for next iteration (stay in this lane!)
        float Cacc = 0.f;
        #pragma unroll
        for (int p = 0; p < PP; ++p) {
            const float wp = __fdividef(1.f, 2.f * sg[p] + EPSF);
            A_r[p]  = wp;
            B2_r[p] = 2.f * wp * mu[p];
            Cacc = fmaf(wp * mu[p], mu[p], Cacc);
        }
        cl2 = cl - Cacc;
    }

    // outputs from iteration 2's M-step (wave 0, lanes 0..31 own them)
    if (tid < 32) {
        float4* mo = (float4*)(out + MU_OFF  + (size_t)pos * (COUT * PP) + c * PP);
        float4* so = (float4*)(out + SIG_OFF + (size_t)pos * (COUT * PP) + c * PP);
        #pragma unroll
        for (int q = 0; q < 4; ++q) {
            mo[q] = make_float4(mu[4*q], mu[4*q+1], mu[4*q+2], mu[4*q+3]);
            so[q] = make_float4(sg[4*q], sg[4*q+1], sg[4*q+2], sg[4*q+3]);
        }
        out[A_OFF + pos * COUT + c] = ao;
    }
}

extern "C" void kernel_launch(void* const* d_in, const int* in_sizes, int n_in,
                              void* d_out, int out_size, void* d_ws, size_t ws_size,
                              hipStream_t stream) {
    const float* V  = (const float*)d_in[0];
    const float* a  = (const float*)d_in[1];
    const float* Bu = (const float*)d_in[2];
    const float* Ba = (const float*)d_in[3];
    const float* R  = (const float*)d_in[4];
    float* out = (float*)d_out;
    em_routing_kernel<<<NPOS, 256, 0, stream>>>(V, a, Bu, Ba, R, out);
}